// Round 1
// baseline (4400.179 us; speedup 1.0000x reference)
//
#include <hip/hip_runtime.h>

#define B_    2048
#define IDX_  32
#define NDIM_ 128
#define SDIM_ 64
#define EDGES 262144
#define NNODE 65536   // B_*IDX_

__device__ __forceinline__ float sigf(float x) { return 1.0f / (1.0f + __expf(-x)); }

// ---------------------------------------------------------------------------
// proj: P1[n][o] = dot(hn[n], W[o][0:128])   + msg_b[o]   (o in [0,128))
//       P2[n][o] = dot(hn[n], W[o][128:256])               (o in [0,128))
// W is msg_W[l], row-major [128][256].
// Block: 64 nodes (lane <-> node), 4 waves; wave wv owns 64 output channels
// (wave-uniform), so weight loads compile to scalar (SGPR) loads.
// ---------------------------------------------------------------------------
__global__ __launch_bounds__(256) void proj_kernel(
    const float* __restrict__ hn, const float* __restrict__ W,
    const float* __restrict__ bias,
    float* __restrict__ P1, float* __restrict__ P2)
{
  __shared__ float x_lds[64 * 36];
  const int t = threadIdx.x;
  const int n0 = blockIdx.x * 64;
  const int lane = t & 63;
  const int wv = __builtin_amdgcn_readfirstlane(t >> 6);

  float acc[64];
#pragma unroll
  for (int j = 0; j < 64; ++j) acc[j] = 0.0f;

  for (int kb = 0; kb < 4; ++kb) {
    __syncthreads();
#pragma unroll
    for (int i = 0; i < 2; ++i) {
      int e = t + 256 * i;                 // 512 float4 = 64 nodes x 32 k
      int n = e >> 3, k4 = e & 7;
      ((float4*)(x_lds + n * 36))[k4] =
          *(const float4*)(hn + (size_t)(n0 + n) * 128 + kb * 32 + k4 * 4);
    }
    __syncthreads();
    float x_r[32];
#pragma unroll
    for (int q = 0; q < 8; ++q) {
      float4 v = *(const float4*)(x_lds + lane * 36 + q * 4);
      x_r[q*4+0] = v.x; x_r[q*4+1] = v.y; x_r[q*4+2] = v.z; x_r[q*4+3] = v.w;
    }
#pragma unroll
    for (int j = 0; j < 64; ++j) {
      const int o = wv * 64 + j;           // wave-uniform
      const float* wrow = W + (size_t)(o & 127) * 256 + ((o >> 7) << 7) + kb * 32;
#pragma unroll
      for (int kk = 0; kk < 32; ++kk)
        acc[j] = fmaf(x_r[kk], wrow[kk], acc[j]);
    }
  }

  const int n = n0 + lane;
#pragma unroll
  for (int j4 = 0; j4 < 16; ++j4) {
    const int o = wv * 64 + j4 * 4;        // uniform -> uniform branch
    float4 v;
    v.x = acc[j4*4+0]; v.y = acc[j4*4+1]; v.z = acc[j4*4+2]; v.w = acc[j4*4+3];
    if (o < 128) {
      v.x += bias[o]; v.y += bias[o+1]; v.z += bias[o+2]; v.w += bias[o+3];
      *(float4*)(P1 + (size_t)n * 128 + o) = v;
    } else {
      *(float4*)(P2 + (size_t)n * 128 + (o - 128)) = v;
    }
  }
}

// ---------------------------------------------------------------------------
// edge: for original edge (a,b):
//   dir a->b: m = relu(P1[b] + P2[a]) -> atomicAdd agg[b]
//   dir b->a: m = relu(P1[a] + P2[b]) -> atomicAdd agg[a]
// 32 threads per edge, float4 per thread. P1 carries msg_b already.
// ---------------------------------------------------------------------------
__global__ __launch_bounds__(256) void edge_kernel(
    const float4* __restrict__ P1, const float4* __restrict__ P2,
    const int* __restrict__ e0, const int* __restrict__ e1,
    float* __restrict__ agg)
{
  const int tid = blockIdx.x * 256 + threadIdx.x;
  const int e = tid >> 5;
  const int l = tid & 31;
  const int a = e0[e];
  const int b = e1[e];
  float4 p1a = P1[(size_t)a * 32 + l];
  float4 p1b = P1[(size_t)b * 32 + l];
  float4 p2a = P2[(size_t)a * 32 + l];
  float4 p2b = P2[(size_t)b * 32 + l];
  float4 m1, m2;
  m1.x = fmaxf(p1b.x + p2a.x, 0.f); m1.y = fmaxf(p1b.y + p2a.y, 0.f);
  m1.z = fmaxf(p1b.z + p2a.z, 0.f); m1.w = fmaxf(p1b.w + p2a.w, 0.f);
  m2.x = fmaxf(p1a.x + p2b.x, 0.f); m2.y = fmaxf(p1a.y + p2b.y, 0.f);
  m2.z = fmaxf(p1a.z + p2b.z, 0.f); m2.w = fmaxf(p1a.w + p2b.w, 0.f);
  float* pb = agg + (size_t)b * 128 + l * 4;
  atomicAdd(pb + 0, m1.x); atomicAdd(pb + 1, m1.y);
  atomicAdd(pb + 2, m1.z); atomicAdd(pb + 3, m1.w);
  float* pa = agg + (size_t)a * 128 + l * 4;
  atomicAdd(pa + 0, m2.x); atomicAdd(pa + 1, m2.y);
  atomicAdd(pa + 2, m2.z); atomicAdd(pa + 3, m2.w);
}

// ---------------------------------------------------------------------------
// gru: fused gi = agg@Wih.T+bih, gh = hin@Whh.T+bhh, gates, hout.
// Block: 64 nodes (lane <-> node); grid.y * 32 + wv*8 gives each wave 8
// channels (wave-uniform) -> 6 weight rows per channel via scalar loads.
// ---------------------------------------------------------------------------
__global__ __launch_bounds__(256) void gru_kernel(
    const float* __restrict__ agg, const float* __restrict__ hin,
    const float* __restrict__ Wih, const float* __restrict__ Whh,
    const float* __restrict__ bih, const float* __restrict__ bhh,
    float* __restrict__ hout)
{
  __shared__ float a_lds[64 * 36];
  __shared__ float h_lds[64 * 36];
  const int t = threadIdx.x;
  const int n0 = blockIdx.x * 64;
  const int lane = t & 63;
  const int wv = __builtin_amdgcn_readfirstlane(t >> 6);
  const int cbase = blockIdx.y * 32 + wv * 8;   // wave-uniform

  float acc[8][6];
#pragma unroll
  for (int j = 0; j < 8; ++j)
#pragma unroll
    for (int s = 0; s < 6; ++s) acc[j][s] = 0.0f;

  for (int kb = 0; kb < 4; ++kb) {
    __syncthreads();
#pragma unroll
    for (int i = 0; i < 2; ++i) {
      int e = t + 256 * i;
      int n = e >> 3, k4 = e & 7;
      ((float4*)(a_lds + n * 36))[k4] =
          *(const float4*)(agg + (size_t)(n0 + n) * 128 + kb * 32 + k4 * 4);
      ((float4*)(h_lds + n * 36))[k4] =
          *(const float4*)(hin + (size_t)(n0 + n) * 128 + kb * 32 + k4 * 4);
    }
    __syncthreads();
    float a_r[32], h_r[32];
#pragma unroll
    for (int q = 0; q < 8; ++q) {
      float4 v = *(const float4*)(a_lds + lane * 36 + q * 4);
      a_r[q*4+0] = v.x; a_r[q*4+1] = v.y; a_r[q*4+2] = v.z; a_r[q*4+3] = v.w;
      float4 u = *(const float4*)(h_lds + lane * 36 + q * 4);
      h_r[q*4+0] = u.x; h_r[q*4+1] = u.y; h_r[q*4+2] = u.z; h_r[q*4+3] = u.w;
    }
#pragma unroll
    for (int j = 0; j < 8; ++j) {
      const int c = cbase + j;
      const float* wir = Wih + (size_t)c * 128 + kb * 32;
      const float* wiz = wir + 128 * 128;
      const float* win = wiz + 128 * 128;
      const float* whr = Whh + (size_t)c * 128 + kb * 32;
      const float* whz = whr + 128 * 128;
      const float* whn = whz + 128 * 128;
#pragma unroll
      for (int kk = 0; kk < 32; ++kk) {
        acc[j][0] = fmaf(a_r[kk], wir[kk], acc[j][0]);
        acc[j][1] = fmaf(a_r[kk], wiz[kk], acc[j][1]);
        acc[j][2] = fmaf(a_r[kk], win[kk], acc[j][2]);
        acc[j][3] = fmaf(h_r[kk], whr[kk], acc[j][3]);
        acc[j][4] = fmaf(h_r[kk], whz[kk], acc[j][4]);
        acc[j][5] = fmaf(h_r[kk], whn[kk], acc[j][5]);
      }
    }
  }

  const int n = n0 + lane;
  float4 ho0 = *(const float4*)(hin + (size_t)n * 128 + cbase);
  float4 ho1 = *(const float4*)(hin + (size_t)n * 128 + cbase + 4);
  float hov[8] = {ho0.x, ho0.y, ho0.z, ho0.w, ho1.x, ho1.y, ho1.z, ho1.w};
  float out[8];
#pragma unroll
  for (int j = 0; j < 8; ++j) {
    const int c = cbase + j;
    float r  = sigf(acc[j][0] + bih[c]       + acc[j][3] + bhh[c]);
    float z  = sigf(acc[j][1] + bih[128 + c] + acc[j][4] + bhh[128 + c]);
    float nn = tanhf(acc[j][2] + bih[256 + c] + r * (acc[j][5] + bhh[256 + c]));
    out[j] = (1.0f - z) * nn + z * hov[j];
  }
  float4 o0, o1;
  o0.x = out[0]; o0.y = out[1]; o0.z = out[2]; o0.w = out[3];
  o1.x = out[4]; o1.y = out[5]; o1.z = out[6]; o1.w = out[7];
  *(float4*)(hout + (size_t)n * 128 + cbase)     = o0;
  *(float4*)(hout + (size_t)n * 128 + cbase + 4) = o1;
}

// ---------------------------------------------------------------------------
// gated: per graph b (32 nodes):
//   hG[b][s]  = sum_i sigmoid(hn_i . gmW + gmb) * (hn_i . fmW[s] + fmb[s])
//   hGi likewise with the *_init weights. One block per graph.
// ---------------------------------------------------------------------------
__global__ __launch_bounds__(256) void gated_kernel(
    const float* __restrict__ hn,
    const float* __restrict__ fmW,  const float* __restrict__ fmb,
    const float* __restrict__ gmW,  const float* __restrict__ gmb,
    const float* __restrict__ fmiW, const float* __restrict__ fmib,
    const float* __restrict__ gmiW, const float* __restrict__ gmib,
    float* __restrict__ hG, float* __restrict__ hGi)
{
  __shared__ float hn_t[32 * 132];
  __shared__ float g_lds[2][32];
  __shared__ float red[4][2][64];
  const int t = threadIdx.x;
  const int b = blockIdx.x;

#pragma unroll
  for (int i = 0; i < 4; ++i) {
    int e = t + 256 * i;                  // 1024 float4 = 32 nodes x 128
    int n = e >> 5, k4 = e & 31;
    ((float4*)(hn_t + n * 132))[k4] =
        ((const float4*)(hn + (size_t)b * 32 * 128))[e];
  }
  __syncthreads();

  if (t < 64) {
    const int head = t >> 5, i = t & 31;
    const float* gw = head ? gmiW : gmW;
    float s = 0.0f;
    for (int k = 0; k < 128; ++k) s = fmaf(hn_t[i * 132 + k], gw[k], s);
    s += head ? gmib[0] : gmb[0];
    g_lds[head][i] = sigf(s);
  }
  __syncthreads();

  const int s_ = t >> 2;   // 0..63 output channel
  const int q  = t & 3;    // node quarter (8 nodes)
  float accf[8], accfi[8];
#pragma unroll
  for (int i = 0; i < 8; ++i) { accf[i] = 0.0f; accfi[i] = 0.0f; }

  const float4* w4  = (const float4*)(fmW  + (size_t)s_ * 128);
  const float4* wi4 = (const float4*)(fmiW + (size_t)s_ * 128);
  for (int k4 = 0; k4 < 32; ++k4) {
    float4 wf  = w4[k4];
    float4 wfi = wi4[k4];
#pragma unroll
    for (int i = 0; i < 8; ++i) {
      float4 h4 = *(const float4*)(hn_t + (q * 8 + i) * 132 + k4 * 4);
      accf[i]  = fmaf(h4.x, wf.x,  fmaf(h4.y, wf.y,  fmaf(h4.z, wf.z,  fmaf(h4.w, wf.w,  accf[i]))));
      accfi[i] = fmaf(h4.x, wfi.x, fmaf(h4.y, wfi.y, fmaf(h4.z, wfi.z, fmaf(h4.w, wfi.w, accfi[i]))));
    }
  }
  const float fb  = fmb[s_];
  const float fbi = fmib[s_];
  float pf = 0.0f, pfi = 0.0f;
#pragma unroll
  for (int i = 0; i < 8; ++i) {
    const int node = q * 8 + i;
    pf  += g_lds[0][node] * (accf[i]  + fb);
    pfi += g_lds[1][node] * (accfi[i] + fbi);
  }
  red[q][0][s_] = pf;
  red[q][1][s_] = pfi;
  __syncthreads();
  if (t < 64) {
    hG[(size_t)b * 64 + t] = red[0][0][t] + red[1][0][t] + red[2][0][t] + red[3][0][t];
  } else if (t < 128) {
    const int s2 = t - 64;
    hGi[(size_t)b * 64 + s2] = red[0][1][s2] + red[1][1][s2] + red[2][1][s2] + red[3][1][s2];
  }
}

// ---------------------------------------------------------------------------
extern "C" void kernel_launch(void* const* d_in, const int* in_sizes, int n_in,
                              void* d_out, int out_size, void* d_ws, size_t ws_size,
                              hipStream_t stream)
{
  (void)in_sizes; (void)n_in; (void)out_size; (void)ws_size;

  const float* h    = (const float*)d_in[0];
  const float* msgW = (const float*)d_in[1];   // [2,128,256]
  const float* msgb = (const float*)d_in[2];   // [2,128]
  const float* Wih  = (const float*)d_in[3];   // [2,384,128]
  const float* Whh  = (const float*)d_in[4];   // [2,384,128]
  const float* bih  = (const float*)d_in[5];   // [2,384]
  const float* bhh  = (const float*)d_in[6];   // [2,384]
  const float* fmW  = (const float*)d_in[7];
  const float* fmb  = (const float*)d_in[8];
  const float* gmW  = (const float*)d_in[9];
  const float* gmb  = (const float*)d_in[10];
  const float* fmiW = (const float*)d_in[11];
  const float* fmib = (const float*)d_in[12];
  const float* gmiW = (const float*)d_in[13];
  const float* gmib = (const float*)d_in[14];
  const int*   ei   = (const int*)d_in[15];    // [2, E]
  const int* e0 = ei;
  const int* e1 = ei + EDGES;

  const size_t NF = (size_t)NNODE * NDIM_;     // 8,388,608 floats
  float* P1   = (float*)d_ws;
  float* P2   = P1 + NF;
  float* agg  = P2 + NF;
  float* hnws = agg + NF;

  float* out_hn  = (float*)d_out;
  float* out_hG  = out_hn + NF;
  float* out_hGi = out_hG + (size_t)B_ * SDIM_;

  const float* hn_in = h;
  float* hn_out = hnws;
  for (int lyr = 0; lyr < 2; ++lyr) {
    proj_kernel<<<NNODE / 64, 256, 0, stream>>>(
        hn_in, msgW + (size_t)lyr * 128 * 256, msgb + (size_t)lyr * 128, P1, P2);
    hipMemsetAsync(agg, 0, NF * sizeof(float), stream);
    edge_kernel<<<(EDGES * 32) / 256, 256, 0, stream>>>(
        (const float4*)P1, (const float4*)P2, e0, e1, agg);
    gru_kernel<<<dim3(NNODE / 64, 4), 256, 0, stream>>>(
        agg, hn_in,
        Wih + (size_t)lyr * 384 * 128, Whh + (size_t)lyr * 384 * 128,
        bih + (size_t)lyr * 384,       bhh + (size_t)lyr * 384,
        hn_out);
    hn_in  = hn_out;
    hn_out = out_hn;
  }

  gated_kernel<<<B_, 256, 0, stream>>>(
      out_hn, fmW, fmb, gmW, gmb, fmiW, fmib, gmiW, gmib, out_hG, out_hGi);
}

// Round 2
// 430.165 us; speedup vs baseline: 10.2291x; 10.2291x over previous
//
#include <hip/hip_runtime.h>

typedef float f32x4 __attribute__((ext_vector_type(4)));
typedef short short8v __attribute__((ext_vector_type(8)));

#define B_    2048
#define NDIM_ 128
#define SDIM_ 64
#define EDGES 262144
#define NNODE 65536   // B_*32

__device__ __forceinline__ float sigf(float x) { return 1.0f / (1.0f + __expf(-x)); }

__device__ __forceinline__ unsigned short f2bf(float f) {        // RNE, no NaN care
  unsigned int u = __float_as_uint(f);
  return (unsigned short)((u + 0x7FFFu + ((u >> 16) & 1u)) >> 16);
}
__device__ __forceinline__ float bf2f(unsigned int h) {
  return __uint_as_float(h << 16);
}

// ---------------------------------------------------------------------------
// weight conversion fp32 -> bf16 (once per launch)
// ---------------------------------------------------------------------------
__global__ __launch_bounds__(256) void convert_w_kernel(
    const float* __restrict__ msgW, const float* __restrict__ Wih,
    const float* __restrict__ Whh,
    unsigned short* __restrict__ wm, unsigned short* __restrict__ wi,
    unsigned short* __restrict__ wh)
{
  int i = blockIdx.x * 256 + threadIdx.x;
  if (i < 2 * 128 * 256) wm[i] = f2bf(msgW[i]);
  if (i < 2 * 384 * 128) { wi[i] = f2bf(Wih[i]); wh[i] = f2bf(Whh[i]); }
}

// ---------------------------------------------------------------------------
// CSR build: hist -> scan -> scatter.  adjacency: for edge (a,b) add a to
// list[b] and b to list[a]  (matches bidirectional message passing).
// ---------------------------------------------------------------------------
__global__ __launch_bounds__(256) void hist_kernel(
    const int* __restrict__ e0, const int* __restrict__ e1, int* __restrict__ cnt)
{
  int e = blockIdx.x * 256 + threadIdx.x;
  if (e < EDGES) {
    atomicAdd(&cnt[e1[e]], 1);
    atomicAdd(&cnt[e0[e]], 1);
  }
}

__global__ __launch_bounds__(1024) void scan_kernel(
    const int* __restrict__ cnt, int* __restrict__ offs, int* __restrict__ cur)
{
  __shared__ int part[1024];
  const int t = threadIdx.x;
  const int base = t * 64;
  int s = 0;
  for (int k = 0; k < 64; ++k) s += cnt[base + k];
  part[t] = s;
  __syncthreads();
  for (int off = 1; off < 1024; off <<= 1) {
    int y = (t >= off) ? part[t - off] : 0;
    __syncthreads();
    part[t] += y;
    __syncthreads();
  }
  int run = part[t] - s;                 // exclusive
  for (int k = 0; k < 64; ++k) {
    offs[base + k] = run; cur[base + k] = run;
    run += cnt[base + k];
  }
  if (t == 1023) offs[NNODE] = run;
}

__global__ __launch_bounds__(256) void scatter_kernel(
    const int* __restrict__ e0, const int* __restrict__ e1,
    int* __restrict__ cur, int* __restrict__ adj)
{
  int e = blockIdx.x * 256 + threadIdx.x;
  if (e < EDGES) {
    int a = e0[e], b = e1[e];
    int p = atomicAdd(&cur[b], 1); adj[p] = a;
    int q = atomicAdd(&cur[a], 1); adj[q] = b;
  }
}

// ---------------------------------------------------------------------------
// proj (MFMA): P1[n][o] = dot(hn[n], W[o][0:128]) + msg_b[o]   (bf16 out)
//              P2[n][o] = dot(hn[n], W[o][128:256])             (bf16 out)
// Block: 64 nodes, 4 waves; wave wv covers 64 of the 256 fused out-channels.
// ---------------------------------------------------------------------------
__global__ __launch_bounds__(256) void proj_mfma_kernel(
    const float* __restrict__ hn, const unsigned short* __restrict__ Wbf,
    const float* __restrict__ msgb,
    unsigned short* __restrict__ P1, unsigned short* __restrict__ P2)
{
  __shared__ unsigned short xl[64 * 136];
  const int t = threadIdx.x, lane = t & 63, wv = t >> 6;
  const int n0 = blockIdx.x * 64;

  {   // stage hn tile fp32 -> bf16 into LDS
    const int row = t >> 2, q = t & 3;
#pragma unroll
    for (int i = 0; i < 8; ++i) {
      int k4 = q * 8 + i;
      float4 v = *(const float4*)(hn + (size_t)(n0 + row) * 128 + k4 * 4);
      unsigned long long pk = (unsigned long long)f2bf(v.x)
          | ((unsigned long long)f2bf(v.y) << 16)
          | ((unsigned long long)f2bf(v.z) << 32)
          | ((unsigned long long)f2bf(v.w) << 48);
      *(unsigned long long*)(xl + row * 136 + k4 * 4) = pk;
    }
  }
  __syncthreads();

  const int cb = wv * 64;
  const int rlo = lane & 15;      // A row / B col / D col within tile
  const int kg  = lane >> 4;
  f32x4 acc[4][4];
#pragma unroll
  for (int mt = 0; mt < 4; ++mt)
#pragma unroll
    for (int nt = 0; nt < 4; ++nt) acc[mt][nt] = (f32x4){0.f, 0.f, 0.f, 0.f};

  for (int kb = 0; kb < 4; ++kb) {
    const int koff = kb * 32 + kg * 8;
    short8v a[4];
#pragma unroll
    for (int mt = 0; mt < 4; ++mt)
      a[mt] = *(const short8v*)(xl + (mt * 16 + rlo) * 136 + koff);
#pragma unroll
    for (int nt = 0; nt < 4; ++nt) {
      int u = cb + nt * 16 + rlo;
      short8v b = *(const short8v*)(Wbf + (size_t)(u & 127) * 256 + ((u >> 7) << 7) + koff);
#pragma unroll
      for (int mt = 0; mt < 4; ++mt)
        acc[mt][nt] = __builtin_amdgcn_mfma_f32_16x16x32_bf16(a[mt], b, acc[mt][nt], 0, 0, 0);
    }
  }

  const int r0 = (lane >> 4) * 4;
#pragma unroll
  for (int nt = 0; nt < 4; ++nt) {
    int u = cb + nt * 16 + rlo;
    float bias = (u < 128) ? msgb[u] : 0.0f;
#pragma unroll
    for (int mt = 0; mt < 4; ++mt)
#pragma unroll
      for (int r = 0; r < 4; ++r) {
        int node = n0 + mt * 16 + r0 + r;
        unsigned short hv = f2bf(acc[mt][nt][r] + bias);
        if (u < 128) P1[(size_t)node * 128 + u] = hv;
        else         P2[(size_t)node * 128 + (u - 128)] = hv;
      }
  }
}

// ---------------------------------------------------------------------------
// agg (CSR): one wave per node v:  agg[v] = sum_{u in adj[v]} relu(P1[v]+P2[u])
// lane handles 2 channels; each neighbor row read is one coalesced 256B row.
// ---------------------------------------------------------------------------
__global__ __launch_bounds__(256) void agg_kernel(
    const unsigned short* __restrict__ P1, const unsigned short* __restrict__ P2,
    const int* __restrict__ offs, const int* __restrict__ adj,
    float* __restrict__ agg)
{
  const int v = blockIdx.x * 4 + (threadIdx.x >> 6);
  const int lane = threadIdx.x & 63;
  const int c0 = lane * 2;
  unsigned int p1 = *(const unsigned int*)(P1 + (size_t)v * 128 + c0);
  const float p1x = bf2f(p1 & 0xFFFFu), p1y = bf2f(p1 >> 16);
  float sx = 0.f, sy = 0.f;
  const int beg = offs[v], end = offs[v + 1];
  for (int j = beg; j < end; ++j) {
    int u = adj[j];
    unsigned int p2 = *(const unsigned int*)(P2 + (size_t)u * 128 + c0);
    sx += fmaxf(p1x + bf2f(p2 & 0xFFFFu), 0.f);
    sy += fmaxf(p1y + bf2f(p2 >> 16), 0.f);
  }
  float2 o; o.x = sx; o.y = sy;
  *(float2*)(agg + (size_t)v * 128 + c0) = o;
}

// ---------------------------------------------------------------------------
// gru (MFMA, fused): gi = agg@Wih.T, gh = hin@Whh.T, gates, hout.
// Block: 64 nodes, 4 waves; grid.y=2; wave covers 16 channels (r,z,n rows).
// ---------------------------------------------------------------------------
__global__ __launch_bounds__(256) void gru_mfma_kernel(
    const float* __restrict__ agg, const float* __restrict__ hin,
    const unsigned short* __restrict__ Wi, const unsigned short* __restrict__ Wh,
    const float* __restrict__ bih, const float* __restrict__ bhh,
    float* __restrict__ hout)
{
  __shared__ unsigned short al[64 * 136];
  __shared__ unsigned short hl[64 * 136];
  const int t = threadIdx.x, lane = t & 63, wv = t >> 6;
  const int n0 = blockIdx.x * 64;

  {   // stage agg + hin tiles fp32 -> bf16
    const int row = t >> 2, q = t & 3;
#pragma unroll
    for (int i = 0; i < 8; ++i) {
      int k4 = q * 8 + i;
      float4 v = *(const float4*)(agg + (size_t)(n0 + row) * 128 + k4 * 4);
      unsigned long long pk = (unsigned long long)f2bf(v.x)
          | ((unsigned long long)f2bf(v.y) << 16)
          | ((unsigned long long)f2bf(v.z) << 32)
          | ((unsigned long long)f2bf(v.w) << 48);
      *(unsigned long long*)(al + row * 136 + k4 * 4) = pk;
      float4 u = *(const float4*)(hin + (size_t)(n0 + row) * 128 + k4 * 4);
      unsigned long long ph = (unsigned long long)f2bf(u.x)
          | ((unsigned long long)f2bf(u.y) << 16)
          | ((unsigned long long)f2bf(u.z) << 32)
          | ((unsigned long long)f2bf(u.w) << 48);
      *(unsigned long long*)(hl + row * 136 + k4 * 4) = ph;
    }
  }
  __syncthreads();

  const int cb = blockIdx.y * 64 + wv * 16;   // 16 channels per wave
  const int rlo = lane & 15;
  const int kg  = lane >> 4;
  f32x4 ai[4][3], ah[4][3];
#pragma unroll
  for (int mt = 0; mt < 4; ++mt)
#pragma unroll
    for (int g = 0; g < 3; ++g) { ai[mt][g] = (f32x4){0,0,0,0}; ah[mt][g] = (f32x4){0,0,0,0}; }

  for (int kb = 0; kb < 4; ++kb) {
    const int koff = kb * 32 + kg * 8;
    short8v aa[4], ha[4];
#pragma unroll
    for (int mt = 0; mt < 4; ++mt) {
      aa[mt] = *(const short8v*)(al + (mt * 16 + rlo) * 136 + koff);
      ha[mt] = *(const short8v*)(hl + (mt * 16 + rlo) * 136 + koff);
    }
#pragma unroll
    for (int g = 0; g < 3; ++g) {
      const size_t wrow = (size_t)(g * 128 + cb + rlo) * 128 + koff;
      short8v bi = *(const short8v*)(Wi + wrow);
      short8v bh = *(const short8v*)(Wh + wrow);
#pragma unroll
      for (int mt = 0; mt < 4; ++mt) {
        ai[mt][g] = __builtin_amdgcn_mfma_f32_16x16x32_bf16(aa[mt], bi, ai[mt][g], 0, 0, 0);
        ah[mt][g] = __builtin_amdgcn_mfma_f32_16x16x32_bf16(ha[mt], bh, ah[mt][g], 0, 0, 0);
      }
    }
  }

  const int c  = cb + rlo;
  const int r0 = (lane >> 4) * 4;
  const float b_ir = bih[c], b_iz = bih[128 + c], b_in = bih[256 + c];
  const float b_hr = bhh[c], b_hz = bhh[128 + c], b_hn = bhh[256 + c];
#pragma unroll
  for (int mt = 0; mt < 4; ++mt)
#pragma unroll
    for (int r = 0; r < 4; ++r) {
      int node = n0 + mt * 16 + r0 + r;
      float hv = hin[(size_t)node * 128 + c];
      float rg = sigf(ai[mt][0][r] + b_ir + ah[mt][0][r] + b_hr);
      float z  = sigf(ai[mt][1][r] + b_iz + ah[mt][1][r] + b_hz);
      float nn = tanhf(ai[mt][2][r] + b_in + rg * (ah[mt][2][r] + b_hn));
      hout[(size_t)node * 128 + c] = (1.0f - z) * nn + z * hv;
    }
}

// ---------------------------------------------------------------------------
// gated readout (unchanged, fp32): one block per graph.
// ---------------------------------------------------------------------------
__global__ __launch_bounds__(256) void gated_kernel(
    const float* __restrict__ hn,
    const float* __restrict__ fmW,  const float* __restrict__ fmb,
    const float* __restrict__ gmW,  const float* __restrict__ gmb,
    const float* __restrict__ fmiW, const float* __restrict__ fmib,
    const float* __restrict__ gmiW, const float* __restrict__ gmib,
    float* __restrict__ hG, float* __restrict__ hGi)
{
  __shared__ float hn_t[32 * 132];
  __shared__ float g_lds[2][32];
  __shared__ float red[4][2][64];
  const int t = threadIdx.x;
  const int b = blockIdx.x;

#pragma unroll
  for (int i = 0; i < 4; ++i) {
    int e = t + 256 * i;
    int n = e >> 5, k4 = e & 31;
    ((float4*)(hn_t + n * 132))[k4] = ((const float4*)(hn + (size_t)b * 32 * 128))[e];
  }
  __syncthreads();

  if (t < 64) {
    const int head = t >> 5, i = t & 31;
    const float* gw = head ? gmiW : gmW;
    float s = 0.0f;
    for (int k = 0; k < 128; ++k) s = fmaf(hn_t[i * 132 + k], gw[k], s);
    s += head ? gmib[0] : gmb[0];
    g_lds[head][i] = sigf(s);
  }
  __syncthreads();

  const int s_ = t >> 2;
  const int q  = t & 3;
  float accf[8], accfi[8];
#pragma unroll
  for (int i = 0; i < 8; ++i) { accf[i] = 0.0f; accfi[i] = 0.0f; }

  const float4* w4  = (const float4*)(fmW  + (size_t)s_ * 128);
  const float4* wi4 = (const float4*)(fmiW + (size_t)s_ * 128);
  for (int k4 = 0; k4 < 32; ++k4) {
    float4 wf  = w4[k4];
    float4 wfi = wi4[k4];
#pragma unroll
    for (int i = 0; i < 8; ++i) {
      float4 h4 = *(const float4*)(hn_t + (q * 8 + i) * 132 + k4 * 4);
      accf[i]  = fmaf(h4.x, wf.x,  fmaf(h4.y, wf.y,  fmaf(h4.z, wf.z,  fmaf(h4.w, wf.w,  accf[i]))));
      accfi[i] = fmaf(h4.x, wfi.x, fmaf(h4.y, wfi.y, fmaf(h4.z, wfi.z, fmaf(h4.w, wfi.w, accfi[i]))));
    }
  }
  const float fb  = fmb[s_];
  const float fbi = fmib[s_];
  float pf = 0.0f, pfi = 0.0f;
#pragma unroll
  for (int i = 0; i < 8; ++i) {
    const int node = q * 8 + i;
    pf  += g_lds[0][node] * (accf[i]  + fb);
    pfi += g_lds[1][node] * (accfi[i] + fbi);
  }
  red[q][0][s_] = pf;
  red[q][1][s_] = pfi;
  __syncthreads();
  if (t < 64) {
    hG[(size_t)b * 64 + t] = red[0][0][t] + red[1][0][t] + red[2][0][t] + red[3][0][t];
  } else if (t < 128) {
    const int s2 = t - 64;
    hGi[(size_t)b * 64 + s2] = red[0][1][s2] + red[1][1][s2] + red[2][1][s2] + red[3][1][s2];
  }
}

// ---------------------------------------------------------------------------
extern "C" void kernel_launch(void* const* d_in, const int* in_sizes, int n_in,
                              void* d_out, int out_size, void* d_ws, size_t ws_size,
                              hipStream_t stream)
{
  (void)in_sizes; (void)n_in; (void)out_size; (void)ws_size;

  const float* h    = (const float*)d_in[0];
  const float* msgW = (const float*)d_in[1];   // [2,128,256]
  const float* msgb = (const float*)d_in[2];   // [2,128]
  const float* Wih  = (const float*)d_in[3];   // [2,384,128]
  const float* Whh  = (const float*)d_in[4];   // [2,384,128]
  const float* bih  = (const float*)d_in[5];
  const float* bhh  = (const float*)d_in[6];
  const float* fmW  = (const float*)d_in[7];
  const float* fmb  = (const float*)d_in[8];
  const float* gmW  = (const float*)d_in[9];
  const float* gmb  = (const float*)d_in[10];
  const float* fmiW = (const float*)d_in[11];
  const float* fmib = (const float*)d_in[12];
  const float* gmiW = (const float*)d_in[13];
  const float* gmib = (const float*)d_in[14];
  const int*   ei   = (const int*)d_in[15];    // [2, E] (int32 from harness)
  const int* e0 = ei;
  const int* e1 = ei + EDGES;

  // ---- workspace carve (bytes) ----
  char* w = (char*)d_ws;
  const size_t NF = (size_t)NNODE * NDIM_;
  unsigned short* P1bf = (unsigned short*)w;  w += NF * 2;                 // 16.8MB
  unsigned short* P2bf = (unsigned short*)w;  w += NF * 2;                 // 16.8MB
  float* agg = (float*)w;                     w += NF * 4;                 // 33.6MB
  float* hn1 = (float*)w;                     w += NF * 4;                 // 33.6MB
  int* cnt  = (int*)w;                        w += (size_t)NNODE * 4;
  int* offs = (int*)w;                        w += (size_t)(NNODE + 64) * 4;
  int* cur  = (int*)w;                        w += (size_t)NNODE * 4;
  int* adj  = (int*)w;                        w += (size_t)2 * EDGES * 4;  // 2.1MB
  unsigned short* wm = (unsigned short*)w;    w += (size_t)2 * 128 * 256 * 2;
  unsigned short* wi = (unsigned short*)w;    w += (size_t)2 * 384 * 128 * 2;
  unsigned short* wh = (unsigned short*)w;    w += (size_t)2 * 384 * 128 * 2;

  float* out_hn  = (float*)d_out;
  float* out_hG  = out_hn + NF;
  float* out_hGi = out_hG + (size_t)B_ * SDIM_;

  // ---- one-time per launch: weights + CSR ----
  convert_w_kernel<<<(2 * 384 * 128 + 255) / 256, 256, 0, stream>>>(
      msgW, Wih, Whh, wm, wi, wh);
  hipMemsetAsync(cnt, 0, (size_t)NNODE * 4, stream);
  hist_kernel<<<EDGES / 256, 256, 0, stream>>>(e0, e1, cnt);
  scan_kernel<<<1, 1024, 0, stream>>>(cnt, offs, cur);
  scatter_kernel<<<EDGES / 256, 256, 0, stream>>>(e0, e1, cur, adj);

  // ---- layers ----
  const float* hn_in = h;
  float* hn_out = hn1;
  for (int lyr = 0; lyr < 2; ++lyr) {
    proj_mfma_kernel<<<NNODE / 64, 256, 0, stream>>>(
        hn_in, wm + (size_t)lyr * 128 * 256, msgb + (size_t)lyr * 128, P1bf, P2bf);
    agg_kernel<<<NNODE / 4, 256, 0, stream>>>(P1bf, P2bf, offs, adj, agg);
    gru_mfma_kernel<<<dim3(NNODE / 64, 2), 256, 0, stream>>>(
        agg, hn_in,
        wi + (size_t)lyr * 384 * 128, wh + (size_t)lyr * 384 * 128,
        bih + (size_t)lyr * 384,      bhh + (size_t)lyr * 384,
        hn_out);
    hn_in  = hn_out;
    hn_out = out_hn;
  }

  gated_kernel<<<B_, 256, 0, stream>>>(
      out_hn, fmW, fmb, gmW, gmb, fmiW, fmib, gmiW, gmib, out_hG, out_hGi);
}

// Round 3
// 366.116 us; speedup vs baseline: 12.0185x; 1.1749x over previous
//
#include <hip/hip_runtime.h>

typedef float f32x4 __attribute__((ext_vector_type(4)));
typedef short short8v __attribute__((ext_vector_type(8)));

#define B_    2048
#define NDIM_ 128
#define SDIM_ 64
#define EDGES 262144
#define NNODE 65536   // B_*32

__device__ __forceinline__ float sigf(float x) { return 1.0f / (1.0f + __expf(-x)); }

__device__ __forceinline__ unsigned short f2bf(float f) {        // RNE
  unsigned int u = __float_as_uint(f);
  return (unsigned short)((u + 0x7FFFu + ((u >> 16) & 1u)) >> 16);
}
__device__ __forceinline__ float bf2f(unsigned int h) {
  return __uint_as_float(h << 16);
}
__device__ __forceinline__ unsigned int pack2(float a, float b) {
  return (unsigned int)f2bf(a) | ((unsigned int)f2bf(b) << 16);
}

// ---------------------------------------------------------------------------
// one-time conversions
// ---------------------------------------------------------------------------
__global__ __launch_bounds__(256) void convert_w_kernel(
    const float* __restrict__ msgW, const float* __restrict__ Wih,
    const float* __restrict__ Whh,
    unsigned short* __restrict__ wm, unsigned short* __restrict__ wi,
    unsigned short* __restrict__ wh)
{
  int i = blockIdx.x * 256 + threadIdx.x;
  if (i < 2 * 128 * 256) wm[i] = f2bf(msgW[i]);
  if (i < 2 * 384 * 128) { wi[i] = f2bf(Wih[i]); wh[i] = f2bf(Whh[i]); }
}

__global__ __launch_bounds__(256) void convert_h_kernel(
    const float* __restrict__ h, unsigned short* __restrict__ hb)
{
  size_t i = (size_t)(blockIdx.x * 256 + threadIdx.x) * 8;
  float4 a = *(const float4*)(h + i);
  float4 b = *(const float4*)(h + i + 4);
  uint4 o;
  o.x = pack2(a.x, a.y); o.y = pack2(a.z, a.w);
  o.z = pack2(b.x, b.y); o.w = pack2(b.z, b.w);
  *(uint4*)(hb + i) = o;
}

// ---------------------------------------------------------------------------
// CSR build
// ---------------------------------------------------------------------------
__global__ __launch_bounds__(256) void hist_kernel(
    const int* __restrict__ e0, const int* __restrict__ e1, int* __restrict__ cnt)
{
  int e = blockIdx.x * 256 + threadIdx.x;
  if (e < EDGES) {
    atomicAdd(&cnt[e1[e]], 1);
    atomicAdd(&cnt[e0[e]], 1);
  }
}

__global__ __launch_bounds__(1024) void scan_kernel(
    const int* __restrict__ cnt, int* __restrict__ offs, int* __restrict__ cur)
{
  __shared__ int part[1024];
  const int t = threadIdx.x;
  const int base = t * 64;
  int s = 0;
  for (int k = 0; k < 64; ++k) s += cnt[base + k];
  part[t] = s;
  __syncthreads();
  for (int off = 1; off < 1024; off <<= 1) {
    int y = (t >= off) ? part[t - off] : 0;
    __syncthreads();
    part[t] += y;
    __syncthreads();
  }
  int run = part[t] - s;                 // exclusive
  for (int k = 0; k < 64; ++k) {
    offs[base + k] = run; cur[base + k] = run;
    run += cnt[base + k];
  }
  if (t == 1023) offs[NNODE] = run;
}

__global__ __launch_bounds__(256) void scatter_kernel(
    const int* __restrict__ e0, const int* __restrict__ e1,
    int* __restrict__ cur, int* __restrict__ adj)
{
  int e = blockIdx.x * 256 + threadIdx.x;
  if (e < EDGES) {
    int a = e0[e], b = e1[e];
    int p = atomicAdd(&cur[b], 1); adj[p] = a;
    int q = atomicAdd(&cur[a], 1); adj[q] = b;
  }
}

// ---------------------------------------------------------------------------
// proj (MFMA, bf16 in/out): P1 = hn@W1.T + msgb, P2 = hn@W2.T
// Block: 64 nodes, 4 waves x 64 channels. Transposed epilogue via LDS.
// ---------------------------------------------------------------------------
__global__ __launch_bounds__(256) void proj_mfma_kernel(
    const unsigned short* __restrict__ hb, const unsigned short* __restrict__ Wbf,
    const float* __restrict__ msgb,
    unsigned short* __restrict__ P1, unsigned short* __restrict__ P2)
{
  __shared__ unsigned short xl[64 * 136];
  __shared__ unsigned short ol[64 * 264];
  const int t = threadIdx.x, lane = t & 63, wv = t >> 6;
  const int n0 = blockIdx.x * 64;

  // stage 64x128 bf16 tile (pure copy, coalesced 16B)
#pragma unroll
  for (int i = 0; i < 4; ++i) {
    int id = t + 256 * i;
    int row = id >> 4, ch = id & 15;
    *(uint4*)(xl + row * 136 + ch * 8) =
        *(const uint4*)(hb + (size_t)(n0 + row) * 128 + ch * 8);
  }
  __syncthreads();

  const int cb = wv * 64;
  const int rlo = lane & 15;
  const int kg  = lane >> 4;
  f32x4 acc[4][4];
#pragma unroll
  for (int mt = 0; mt < 4; ++mt)
#pragma unroll
    for (int nt = 0; nt < 4; ++nt) acc[mt][nt] = (f32x4){0.f, 0.f, 0.f, 0.f};

  for (int kb = 0; kb < 4; ++kb) {
    const int koff = kb * 32 + kg * 8;
    short8v a[4];
#pragma unroll
    for (int mt = 0; mt < 4; ++mt)
      a[mt] = *(const short8v*)(xl + (mt * 16 + rlo) * 136 + koff);
#pragma unroll
    for (int nt = 0; nt < 4; ++nt) {
      int u = cb + nt * 16 + rlo;
      short8v b = *(const short8v*)(Wbf + (size_t)(u & 127) * 256 + ((u >> 7) << 7) + koff);
#pragma unroll
      for (int mt = 0; mt < 4; ++mt)
        acc[mt][nt] = __builtin_amdgcn_mfma_f32_16x16x32_bf16(a[mt], b, acc[mt][nt], 0, 0, 0);
    }
  }

  // transpose epilogue: D col = channel, row = node
#pragma unroll
  for (int nt = 0; nt < 4; ++nt) {
    int u = cb + nt * 16 + rlo;
    float bias = (u < 128) ? msgb[u] : 0.0f;
#pragma unroll
    for (int mt = 0; mt < 4; ++mt)
#pragma unroll
      for (int r = 0; r < 4; ++r)
        ol[(mt * 16 + kg * 4 + r) * 264 + u] = f2bf(acc[mt][nt][r] + bias);
  }
  __syncthreads();

  const int row = t >> 2, seg = t & 3;          // 64B per thread per half
#pragma unroll
  for (int p = 0; p < 2; ++p) {
    const unsigned short* src = ol + row * 264 + p * 128 + seg * 32;
    unsigned short* dst = (p ? P2 : P1) + (size_t)(n0 + row) * 128 + seg * 32;
    *(uint4*)(dst)      = *(const uint4*)(src);
    *(uint4*)(dst + 8)  = *(const uint4*)(src + 8);
    *(uint4*)(dst + 16) = *(const uint4*)(src + 16);
    *(uint4*)(dst + 24) = *(const uint4*)(src + 24);
  }
}

// ---------------------------------------------------------------------------
// agg (CSR, bf16 in/out): wave per node v, lane = 2 channels.
// ---------------------------------------------------------------------------
__global__ __launch_bounds__(256) void agg_kernel(
    const unsigned short* __restrict__ P1, const unsigned short* __restrict__ P2,
    const int* __restrict__ offs, const int* __restrict__ adj,
    unsigned short* __restrict__ aggb)
{
  const int v = blockIdx.x * 4 + (threadIdx.x >> 6);
  const int lane = threadIdx.x & 63;
  unsigned int p1 = *(const unsigned int*)(P1 + (size_t)v * 128 + lane * 2);
  const float p1x = bf2f(p1 & 0xFFFFu), p1y = bf2f(p1 >> 16);
  float sx = 0.f, sy = 0.f;
  const int beg = offs[v], end = offs[v + 1];
  int j = beg;
  for (; j + 4 <= end; j += 4) {
    int u0 = adj[j], u1 = adj[j + 1], u2 = adj[j + 2], u3 = adj[j + 3];
    unsigned int q0 = *(const unsigned int*)(P2 + (size_t)u0 * 128 + lane * 2);
    unsigned int q1 = *(const unsigned int*)(P2 + (size_t)u1 * 128 + lane * 2);
    unsigned int q2 = *(const unsigned int*)(P2 + (size_t)u2 * 128 + lane * 2);
    unsigned int q3 = *(const unsigned int*)(P2 + (size_t)u3 * 128 + lane * 2);
    sx += fmaxf(p1x + bf2f(q0 & 0xFFFFu), 0.f) + fmaxf(p1x + bf2f(q1 & 0xFFFFu), 0.f)
        + fmaxf(p1x + bf2f(q2 & 0xFFFFu), 0.f) + fmaxf(p1x + bf2f(q3 & 0xFFFFu), 0.f);
    sy += fmaxf(p1y + bf2f(q0 >> 16), 0.f) + fmaxf(p1y + bf2f(q1 >> 16), 0.f)
        + fmaxf(p1y + bf2f(q2 >> 16), 0.f) + fmaxf(p1y + bf2f(q3 >> 16), 0.f);
  }
  for (; j < end; ++j) {
    int u = adj[j];
    unsigned int q = *(const unsigned int*)(P2 + (size_t)u * 128 + lane * 2);
    sx += fmaxf(p1x + bf2f(q & 0xFFFFu), 0.f);
    sy += fmaxf(p1y + bf2f(q >> 16), 0.f);
  }
  *(unsigned int*)(aggb + (size_t)v * 128 + lane * 2) = pack2(sx, sy);
}

// ---------------------------------------------------------------------------
// gru (MFMA, bf16 in, bf16 or widened-fp32 out, fused gates)
// Block: 64 nodes, 4 waves x 16 channels; grid.y=2 covers 128 channels.
// ---------------------------------------------------------------------------
__global__ __launch_bounds__(256) void gru_mfma_kernel(
    const unsigned short* __restrict__ aggb, const unsigned short* __restrict__ hnb,
    const unsigned short* __restrict__ Wi, const unsigned short* __restrict__ Wh,
    const float* __restrict__ bih, const float* __restrict__ bhh,
    unsigned short* __restrict__ houtb, float* __restrict__ houtf, int last)
{
  __shared__ unsigned short al[64 * 136];
  __shared__ unsigned short hl[64 * 136];
  const int t = threadIdx.x, lane = t & 63, wv = t >> 6;
  const int n0 = blockIdx.x * 64;
  const int yoff = blockIdx.y * 64;

  // stage agg + hin tiles (pure bf16 copies)
#pragma unroll
  for (int i = 0; i < 8; ++i) {
    int id = t + 256 * i;                      // 0..2047
    int row = (id >> 4) & 63, ch = id & 15;
    const unsigned short* src = (i < 4) ? aggb : hnb;
    unsigned short* dst = (i < 4) ? al : hl;
    *(uint4*)(dst + row * 136 + ch * 8) =
        *(const uint4*)(src + (size_t)(n0 + row) * 128 + ch * 8);
  }
  __syncthreads();

  const int rlo = lane & 15;
  const int kg  = lane >> 4;
  const int c   = yoff + wv * 16 + rlo;        // global channel, wave-uniform base
  f32x4 ai[4][3], ah[4][3];
#pragma unroll
  for (int mt = 0; mt < 4; ++mt)
#pragma unroll
    for (int g = 0; g < 3; ++g) { ai[mt][g] = (f32x4){0,0,0,0}; ah[mt][g] = (f32x4){0,0,0,0}; }

  for (int kb = 0; kb < 4; ++kb) {
    const int koff = kb * 32 + kg * 8;
    short8v aa[4], ha[4];
#pragma unroll
    for (int mt = 0; mt < 4; ++mt) {
      aa[mt] = *(const short8v*)(al + (mt * 16 + rlo) * 136 + koff);
      ha[mt] = *(const short8v*)(hl + (mt * 16 + rlo) * 136 + koff);
    }
#pragma unroll
    for (int g = 0; g < 3; ++g) {
      const size_t wrow = (size_t)(g * 128 + c) * 128 + koff;
      short8v bi = *(const short8v*)(Wi + wrow);
      short8v bh = *(const short8v*)(Wh + wrow);
#pragma unroll
      for (int mt = 0; mt < 4; ++mt) {
        ai[mt][g] = __builtin_amdgcn_mfma_f32_16x16x32_bf16(aa[mt], bi, ai[mt][g], 0, 0, 0);
        ah[mt][g] = __builtin_amdgcn_mfma_f32_16x16x32_bf16(ha[mt], bh, ah[mt][g], 0, 0, 0);
      }
    }
  }

  const float b_ir = bih[c], b_iz = bih[128 + c], b_in = bih[256 + c];
  const float b_hr = bhh[c], b_hz = bhh[128 + c], b_hn = bhh[256 + c];
  unsigned short ov[4][4];
#pragma unroll
  for (int mt = 0; mt < 4; ++mt)
#pragma unroll
    for (int r = 0; r < 4; ++r) {
      int nl = mt * 16 + kg * 4 + r;
      float hv = bf2f(hl[nl * 136 + c]);
      float rg = sigf(ai[mt][0][r] + b_ir + ah[mt][0][r] + b_hr);
      float z  = sigf(ai[mt][1][r] + b_iz + ah[mt][1][r] + b_hz);
      float nn = tanhf(ai[mt][2][r] + b_in + rg * (ah[mt][2][r] + b_hn));
      ov[mt][r] = f2bf((1.0f - z) * nn + z * hv);
    }

  // transposed store through LDS (reuse al as [64][72])
  __syncthreads();
  unsigned short* ol = al;
  const int cl = wv * 16 + rlo;                // local channel 0..63
#pragma unroll
  for (int mt = 0; mt < 4; ++mt)
#pragma unroll
    for (int r = 0; r < 4; ++r)
      ol[(mt * 16 + kg * 4 + r) * 72 + cl] = ov[mt][r];
  __syncthreads();

  const int row = t >> 2, seg = t & 3;         // 32B (16 ch) per thread
  const unsigned short* src = ol + row * 72 + seg * 16;
  if (!last) {
    unsigned short* dst = houtb + (size_t)(n0 + row) * 128 + yoff + seg * 16;
    *(uint4*)(dst)     = *(const uint4*)(src);
    *(uint4*)(dst + 8) = *(const uint4*)(src + 8);
  } else {
    float* dst = houtf + (size_t)(n0 + row) * 128 + yoff + seg * 16;
#pragma unroll
    for (int q = 0; q < 4; ++q) {
      float4 v;
      v.x = bf2f(src[q * 4 + 0]); v.y = bf2f(src[q * 4 + 1]);
      v.z = bf2f(src[q * 4 + 2]); v.w = bf2f(src[q * 4 + 3]);
      *(float4*)(dst + q * 4) = v;
    }
  }
}

// ---------------------------------------------------------------------------
// gated readout (fp32): one block per graph.
// ---------------------------------------------------------------------------
__global__ __launch_bounds__(256) void gated_kernel(
    const float* __restrict__ hn,
    const float* __restrict__ fmW,  const float* __restrict__ fmb,
    const float* __restrict__ gmW,  const float* __restrict__ gmb,
    const float* __restrict__ fmiW, const float* __restrict__ fmib,
    const float* __restrict__ gmiW, const float* __restrict__ gmib,
    float* __restrict__ hG, float* __restrict__ hGi)
{
  __shared__ float hn_t[32 * 132];
  __shared__ float g_lds[2][32];
  __shared__ float red[4][2][64];
  const int t = threadIdx.x;
  const int b = blockIdx.x;

#pragma unroll
  for (int i = 0; i < 4; ++i) {
    int e = t + 256 * i;
    int n = e >> 5, k4 = e & 31;
    ((float4*)(hn_t + n * 132))[k4] = ((const float4*)(hn + (size_t)b * 32 * 128))[e];
  }
  __syncthreads();

  if (t < 64) {
    const int head = t >> 5, i = t & 31;
    const float* gw = head ? gmiW : gmW;
    float s = 0.0f;
    for (int k = 0; k < 128; ++k) s = fmaf(hn_t[i * 132 + k], gw[k], s);
    s += head ? gmib[0] : gmb[0];
    g_lds[head][i] = sigf(s);
  }
  __syncthreads();

  const int s_ = t >> 2;
  const int q  = t & 3;
  float accf[8], accfi[8];
#pragma unroll
  for (int i = 0; i < 8; ++i) { accf[i] = 0.0f; accfi[i] = 0.0f; }

  const float4* w4  = (const float4*)(fmW  + (size_t)s_ * 128);
  const float4* wi4 = (const float4*)(fmiW + (size_t)s_ * 128);
  for (int k4 = 0; k4 < 32; ++k4) {
    float4 wf  = w4[k4];
    float4 wfi = wi4[k4];
#pragma unroll
    for (int i = 0; i < 8; ++i) {
      float4 h4 = *(const float4*)(hn_t + (q * 8 + i) * 132 + k4 * 4);
      accf[i]  = fmaf(h4.x, wf.x,  fmaf(h4.y, wf.y,  fmaf(h4.z, wf.z,  fmaf(h4.w, wf.w,  accf[i]))));
      accfi[i] = fmaf(h4.x, wfi.x, fmaf(h4.y, wfi.y, fmaf(h4.z, wfi.z, fmaf(h4.w, wfi.w, accfi[i]))));
    }
  }
  const float fb  = fmb[s_];
  const float fbi = fmib[s_];
  float pf = 0.0f, pfi = 0.0f;
#pragma unroll
  for (int i = 0; i < 8; ++i) {
    const int node = q * 8 + i;
    pf  += g_lds[0][node] * (accf[i]  + fb);
    pfi += g_lds[1][node] * (accfi[i] + fbi);
  }
  red[q][0][s_] = pf;
  red[q][1][s_] = pfi;
  __syncthreads();
  if (t < 64) {
    hG[(size_t)b * 64 + t] = red[0][0][t] + red[1][0][t] + red[2][0][t] + red[3][0][t];
  } else if (t < 128) {
    const int s2 = t - 64;
    hGi[(size_t)b * 64 + s2] = red[0][1][s2] + red[1][1][s2] + red[2][1][s2] + red[3][1][s2];
  }
}

// ---------------------------------------------------------------------------
extern "C" void kernel_launch(void* const* d_in, const int* in_sizes, int n_in,
                              void* d_out, int out_size, void* d_ws, size_t ws_size,
                              hipStream_t stream)
{
  (void)in_sizes; (void)n_in; (void)out_size; (void)ws_size;

  const float* h    = (const float*)d_in[0];
  const float* msgW = (const float*)d_in[1];
  const float* msgb = (const float*)d_in[2];
  const float* Wih  = (const float*)d_in[3];
  const float* Whh  = (const float*)d_in[4];
  const float* bih  = (const float*)d_in[5];
  const float* bhh  = (const float*)d_in[6];
  const float* fmW  = (const float*)d_in[7];
  const float* fmb  = (const float*)d_in[8];
  const float* gmW  = (const float*)d_in[9];
  const float* gmb  = (const float*)d_in[10];
  const float* fmiW = (const float*)d_in[11];
  const float* fmib = (const float*)d_in[12];
  const float* gmiW = (const float*)d_in[13];
  const float* gmib = (const float*)d_in[14];
  const int*   ei   = (const int*)d_in[15];
  const int* e0 = ei;
  const int* e1 = ei + EDGES;

  // ---- workspace carve ----
  char* w = (char*)d_ws;
  const size_t NF = (size_t)NNODE * NDIM_;
  unsigned short* P1b  = (unsigned short*)w;  w += NF * 2;    // 16.8MB
  unsigned short* P2b  = (unsigned short*)w;  w += NF * 2;    // 16.8MB
  unsigned short* aggb = (unsigned short*)w;  w += NF * 2;    // 16.8MB
  unsigned short* hb   = (unsigned short*)w;  w += NF * 2;    // 16.8MB
  unsigned short* hnb  = (unsigned short*)w;  w += NF * 2;    // 16.8MB
  int* cnt  = (int*)w;                        w += (size_t)NNODE * 4;
  int* offs = (int*)w;                        w += (size_t)(NNODE + 64) * 4;
  int* cur  = (int*)w;                        w += (size_t)NNODE * 4;
  int* adj  = (int*)w;                        w += (size_t)2 * EDGES * 4;
  unsigned short* wm = (unsigned short*)w;    w += (size_t)2 * 128 * 256 * 2;
  unsigned short* wi = (unsigned short*)w;    w += (size_t)2 * 384 * 128 * 2;
  unsigned short* wh = (unsigned short*)w;    w += (size_t)2 * 384 * 128 * 2;

  float* out_hn  = (float*)d_out;
  float* out_hG  = out_hn + NF;
  float* out_hGi = out_hG + (size_t)B_ * SDIM_;

  // ---- one-time: conversions + CSR ----
  convert_w_kernel<<<(2 * 384 * 128 + 255) / 256, 256, 0, stream>>>(
      msgW, Wih, Whh, wm, wi, wh);
  convert_h_kernel<<<(int)(NF / 8 / 256), 256, 0, stream>>>(h, hb);
  hipMemsetAsync(cnt, 0, (size_t)NNODE * 4, stream);
  hist_kernel<<<EDGES / 256, 256, 0, stream>>>(e0, e1, cnt);
  scan_kernel<<<1, 1024, 0, stream>>>(cnt, offs, cur);
  scatter_kernel<<<EDGES / 256, 256, 0, stream>>>(e0, e1, cur, adj);

  // ---- layers ----
  const unsigned short* hin = hb;
  for (int lyr = 0; lyr < 2; ++lyr) {
    proj_mfma_kernel<<<NNODE / 64, 256, 0, stream>>>(
        hin, wm + (size_t)lyr * 128 * 256, msgb + (size_t)lyr * 128, P1b, P2b);
    agg_kernel<<<NNODE / 4, 256, 0, stream>>>(P1b, P2b, offs, adj, aggb);
    gru_mfma_kernel<<<dim3(NNODE / 64, 2), 256, 0, stream>>>(
        aggb, hin,
        wi + (size_t)lyr * 384 * 128, wh + (size_t)lyr * 384 * 128,
        bih + (size_t)lyr * 384,      bhh + (size_t)lyr * 384,
        hnb, out_hn, lyr);
    hin = hnb;
  }

  gated_kernel<<<B_, 256, 0, stream>>>(
      out_hn, fmW, fmb, gmW, gmb, fmiW, fmib, gmiW, gmib, out_hG, out_hGi);
}

// Round 4
// 316.618 us; speedup vs baseline: 13.8974x; 1.1563x over previous
//
#include <hip/hip_runtime.h>

typedef float f32x4 __attribute__((ext_vector_type(4)));
typedef short short8v __attribute__((ext_vector_type(8)));

#define B_    2048
#define NDIM_ 128
#define SDIM_ 64
#define EDGES 262144
#define NNODE 65536   // B_*32

__device__ __forceinline__ float fastrcp(float x) { return __builtin_amdgcn_rcpf(x); }
__device__ __forceinline__ float sigf(float x) { return fastrcp(1.0f + __expf(-x)); }
__device__ __forceinline__ float tanhfast(float x) {
  // 1 - 2/(1+e^{2x}); +inf -> 1, -inf -> -1 (rcp(inf)=0)
  return 1.0f - 2.0f * fastrcp(1.0f + __expf(2.0f * x));
}

__device__ __forceinline__ unsigned short f2bf(float f) {        // RNE
  unsigned int u = __float_as_uint(f);
  return (unsigned short)((u + 0x7FFFu + ((u >> 16) & 1u)) >> 16);
}
__device__ __forceinline__ float bf2f(unsigned int h) {
  return __uint_as_float(h << 16);
}
__device__ __forceinline__ unsigned int pack2(float a, float b) {
  return (unsigned int)f2bf(a) | ((unsigned int)f2bf(b) << 16);
}

// ---------------------------------------------------------------------------
// one-time conversions + GRU weight packing
//   wrz[l][c][k], c in [0,256): rows 0..127 = r-gate, 128..255 = z-gate;
//                 k<128 -> Wih[l][c%... ][k], k>=128 -> Whh (K=256 fusion)
//   wni[l][c][k] = Wih[l][256+c][k];  wnh[l][c][k] = Whh[l][256+c][k]
// ---------------------------------------------------------------------------
__global__ __launch_bounds__(256) void convert_w_kernel(
    const float* __restrict__ msgW, const float* __restrict__ Wih,
    const float* __restrict__ Whh,
    unsigned short* __restrict__ wm, unsigned short* __restrict__ wrz,
    unsigned short* __restrict__ wni, unsigned short* __restrict__ wnh)
{
  int id = blockIdx.x * 256 + threadIdx.x;       // [0, 131072)
  {
    int l = id >> 16, c = (id >> 8) & 255, k = id & 255;
    const float* base = (k < 128) ? Wih : Whh;
    wrz[id] = f2bf(base[(size_t)l * 384 * 128 + (size_t)c * 128 + (k & 127)]);
  }
  if (id < 2 * 128 * 256) wm[id] = f2bf(msgW[id]);
  if (id < 2 * 128 * 128) {
    int l = id >> 14, c = (id >> 7) & 127, k = id & 127;
    size_t src = (size_t)l * 384 * 128 + (size_t)(256 + c) * 128 + k;
    wni[id] = f2bf(Wih[src]);
    wnh[id] = f2bf(Whh[src]);
  }
}

__global__ __launch_bounds__(256) void convert_h_kernel(
    const float* __restrict__ h, unsigned short* __restrict__ hb)
{
  size_t i = (size_t)(blockIdx.x * 256 + threadIdx.x) * 8;
  float4 a = *(const float4*)(h + i);
  float4 b = *(const float4*)(h + i + 4);
  uint4 o;
  o.x = pack2(a.x, a.y); o.y = pack2(a.z, a.w);
  o.z = pack2(b.x, b.y); o.w = pack2(b.z, b.w);
  *(uint4*)(hb + i) = o;
}

// ---------------------------------------------------------------------------
// CSR build: hist -> 3-phase scan -> scatter
// ---------------------------------------------------------------------------
__global__ __launch_bounds__(256) void hist_kernel(
    const int* __restrict__ e0, const int* __restrict__ e1, int* __restrict__ cnt)
{
  int e = blockIdx.x * 256 + threadIdx.x;
  if (e < EDGES) {
    atomicAdd(&cnt[e1[e]], 1);
    atomicAdd(&cnt[e0[e]], 1);
  }
}

__global__ __launch_bounds__(256) void scan1_kernel(
    const int* __restrict__ cnt, int* __restrict__ offs, int* __restrict__ bsum)
{
  __shared__ int sh[256];
  const int t = threadIdx.x;
  const int i = blockIdx.x * 256 + t;
  int v = cnt[i];
  int x = v;
  sh[t] = x;
  __syncthreads();
#pragma unroll
  for (int off = 1; off < 256; off <<= 1) {
    int y = (t >= off) ? sh[t - off] : 0;
    __syncthreads();
    x += y; sh[t] = x;
    __syncthreads();
  }
  offs[i] = x - v;                       // block-local exclusive
  if (t == 255) bsum[blockIdx.x] = x;
}

__global__ __launch_bounds__(256) void scan2_kernel(int* __restrict__ bsum,
                                                    int* __restrict__ boff)
{
  __shared__ int sh[256];
  const int t = threadIdx.x;
  int v = bsum[t];
  int x = v;
  sh[t] = x;
  __syncthreads();
#pragma unroll
  for (int off = 1; off < 256; off <<= 1) {
    int y = (t >= off) ? sh[t - off] : 0;
    __syncthreads();
    x += y; sh[t] = x;
    __syncthreads();
  }
  boff[t] = x - v;
}

__global__ __launch_bounds__(256) void scan3_kernel(
    const int* __restrict__ cnt, int* __restrict__ offs,
    const int* __restrict__ boff, int* __restrict__ cur)
{
  const int i = blockIdx.x * 256 + threadIdx.x;
  int o = offs[i] + boff[blockIdx.x];
  offs[i] = o; cur[i] = o;
  if (i == NNODE - 1) offs[NNODE] = o + cnt[i];
}

__global__ __launch_bounds__(256) void scatter_kernel(
    const int* __restrict__ e0, const int* __restrict__ e1,
    int* __restrict__ cur, int* __restrict__ adj)
{
  int e = blockIdx.x * 256 + threadIdx.x;
  if (e < EDGES) {
    int a = e0[e], b = e1[e];
    int p = atomicAdd(&cur[b], 1); adj[p] = a;
    int q = atomicAdd(&cur[a], 1); adj[q] = b;
  }
}

// ---------------------------------------------------------------------------
// proj (MFMA, bf16 in/out): P1 = hn@W1.T + msgb, P2 = hn@W2.T
// ---------------------------------------------------------------------------
__global__ __launch_bounds__(256) void proj_mfma_kernel(
    const unsigned short* __restrict__ hb, const unsigned short* __restrict__ Wbf,
    const float* __restrict__ msgb,
    unsigned short* __restrict__ P1, unsigned short* __restrict__ P2)
{
  __shared__ unsigned short xl[64 * 136];
  __shared__ unsigned short ol[64 * 264];
  const int t = threadIdx.x, lane = t & 63, wv = t >> 6;
  const int n0 = blockIdx.x * 64;

#pragma unroll
  for (int i = 0; i < 4; ++i) {
    int id = t + 256 * i;
    int row = id >> 4, ch = id & 15;
    *(uint4*)(xl + row * 136 + ch * 8) =
        *(const uint4*)(hb + (size_t)(n0 + row) * 128 + ch * 8);
  }
  __syncthreads();

  const int cb = wv * 64;
  const int rlo = lane & 15;
  const int kg  = lane >> 4;
  f32x4 acc[4][4];
#pragma unroll
  for (int mt = 0; mt < 4; ++mt)
#pragma unroll
    for (int nt = 0; nt < 4; ++nt) acc[mt][nt] = (f32x4){0.f, 0.f, 0.f, 0.f};

  for (int kb = 0; kb < 4; ++kb) {
    const int koff = kb * 32 + kg * 8;
    short8v a[4];
#pragma unroll
    for (int mt = 0; mt < 4; ++mt)
      a[mt] = *(const short8v*)(xl + (mt * 16 + rlo) * 136 + koff);
#pragma unroll
    for (int nt = 0; nt < 4; ++nt) {
      int u = cb + nt * 16 + rlo;
      short8v b = *(const short8v*)(Wbf + (size_t)(u & 127) * 256 + ((u >> 7) << 7) + koff);
#pragma unroll
      for (int mt = 0; mt < 4; ++mt)
        acc[mt][nt] = __builtin_amdgcn_mfma_f32_16x16x32_bf16(a[mt], b, acc[mt][nt], 0, 0, 0);
    }
  }

#pragma unroll
  for (int nt = 0; nt < 4; ++nt) {
    int u = cb + nt * 16 + rlo;
    float bias = (u < 128) ? msgb[u] : 0.0f;
#pragma unroll
    for (int mt = 0; mt < 4; ++mt)
#pragma unroll
      for (int r = 0; r < 4; ++r)
        ol[(mt * 16 + kg * 4 + r) * 264 + u] = f2bf(acc[mt][nt][r] + bias);
  }
  __syncthreads();

  const int row = t >> 2, seg = t & 3;
#pragma unroll
  for (int p = 0; p < 2; ++p) {
    const unsigned short* src = ol + row * 264 + p * 128 + seg * 32;
    unsigned short* dst = (p ? P2 : P1) + (size_t)(n0 + row) * 128 + seg * 32;
    *(uint4*)(dst)      = *(const uint4*)(src);
    *(uint4*)(dst + 8)  = *(const uint4*)(src + 8);
    *(uint4*)(dst + 16) = *(const uint4*)(src + 16);
    *(uint4*)(dst + 24) = *(const uint4*)(src + 24);
  }
}

// ---------------------------------------------------------------------------
// agg (CSR, bf16 in/out): wave per node v, lane = 2 channels.
// ---------------------------------------------------------------------------
__global__ __launch_bounds__(256) void agg_kernel(
    const unsigned short* __restrict__ P1, const unsigned short* __restrict__ P2,
    const int* __restrict__ offs, const int* __restrict__ adj,
    unsigned short* __restrict__ aggb)
{
  const int v = blockIdx.x * 4 + (threadIdx.x >> 6);
  const int lane = threadIdx.x & 63;
  unsigned int p1 = *(const unsigned int*)(P1 + (size_t)v * 128 + lane * 2);
  const float p1x = bf2f(p1 & 0xFFFFu), p1y = bf2f(p1 >> 16);
  float sx = 0.f, sy = 0.f;
  const int beg = offs[v], end = offs[v + 1];
  int j = beg;
  for (; j + 4 <= end; j += 4) {
    int u0 = adj[j], u1 = adj[j + 1], u2 = adj[j + 2], u3 = adj[j + 3];
    unsigned int q0 = *(const unsigned int*)(P2 + (size_t)u0 * 128 + lane * 2);
    unsigned int q1 = *(const unsigned int*)(P2 + (size_t)u1 * 128 + lane * 2);
    unsigned int q2 = *(const unsigned int*)(P2 + (size_t)u2 * 128 + lane * 2);
    unsigned int q3 = *(const unsigned int*)(P2 + (size_t)u3 * 128 + lane * 2);
    sx += fmaxf(p1x + bf2f(q0 & 0xFFFFu), 0.f) + fmaxf(p1x + bf2f(q1 & 0xFFFFu), 0.f)
        + fmaxf(p1x + bf2f(q2 & 0xFFFFu), 0.f) + fmaxf(p1x + bf2f(q3 & 0xFFFFu), 0.f);
    sy += fmaxf(p1y + bf2f(q0 >> 16), 0.f) + fmaxf(p1y + bf2f(q1 >> 16), 0.f)
        + fmaxf(p1y + bf2f(q2 >> 16), 0.f) + fmaxf(p1y + bf2f(q3 >> 16), 0.f);
  }
  for (; j < end; ++j) {
    int u = adj[j];
    unsigned int q = *(const unsigned int*)(P2 + (size_t)u * 128 + lane * 2);
    sx += fmaxf(p1x + bf2f(q & 0xFFFFu), 0.f);
    sy += fmaxf(p1y + bf2f(q >> 16), 0.f);
  }
  *(unsigned int*)(aggb + (size_t)v * 128 + lane * 2) = pack2(sx, sy);
}

// ---------------------------------------------------------------------------
// gru (MFMA, single dispatch, K=256 fused r/z):
//   stage [agg | hn] as one 64x256 bf16 tile; wave wv -> channels [32wv,32wv+32)
//   acc_r/acc_z over K=256 (wrz), acc_in over agg half (wni), acc_hn over hn
//   half (wnh). Fast exp-based gates. Transposed store via agg half of LDS.
// ---------------------------------------------------------------------------
__global__ __launch_bounds__(256) void gru_mfma_kernel(
    const unsigned short* __restrict__ aggb, const unsigned short* __restrict__ hnb,
    const unsigned short* __restrict__ wrz, const unsigned short* __restrict__ wni,
    const unsigned short* __restrict__ wnh,
    const float* __restrict__ bih, const float* __restrict__ bhh,
    unsigned short* __restrict__ houtb, float* __restrict__ houtf, int last)
{
  __shared__ unsigned short xl[64 * 264];     // cols [0,128)=agg, [128,256)=hn
  const int t = threadIdx.x, lane = t & 63, wv = t >> 6;
  const int n0 = blockIdx.x * 64;

#pragma unroll
  for (int i = 0; i < 8; ++i) {
    int id = t + 256 * i;
    int row = (id >> 4) & 63, ch = id & 15;
    const unsigned short* src = (i < 4) ? aggb : hnb;
    int cb0 = (i < 4) ? 0 : 128;
    *(uint4*)(xl + row * 264 + cb0 + ch * 8) =
        *(const uint4*)(src + (size_t)(n0 + row) * 128 + ch * 8);
  }
  __syncthreads();

  const int rlo = lane & 15, kg = lane >> 4;
  const int cb = wv * 32;                     // this wave's channels
  f32x4 ar[4][2], az[4][2], ain[4][2], ahn[4][2];
#pragma unroll
  for (int mt = 0; mt < 4; ++mt)
#pragma unroll
    for (int nt = 0; nt < 2; ++nt) {
      ar[mt][nt] = (f32x4){0,0,0,0}; az[mt][nt] = (f32x4){0,0,0,0};
      ain[mt][nt] = (f32x4){0,0,0,0}; ahn[mt][nt] = (f32x4){0,0,0,0};
    }

#pragma unroll
  for (int kb = 0; kb < 8; ++kb) {
    const int koff = kb * 32 + kg * 8;        // [0,256)
    short8v a[4];
#pragma unroll
    for (int mt = 0; mt < 4; ++mt)
      a[mt] = *(const short8v*)(xl + (mt * 16 + rlo) * 264 + koff);
#pragma unroll
    for (int nt = 0; nt < 2; ++nt) {
      const int c = cb + nt * 16 + rlo;
      const unsigned short* wr = wrz + (size_t)c * 256 + koff;
      short8v br = *(const short8v*)wr;
      short8v bz = *(const short8v*)(wr + 128 * 256);
#pragma unroll
      for (int mt = 0; mt < 4; ++mt) {
        ar[mt][nt] = __builtin_amdgcn_mfma_f32_16x16x32_bf16(a[mt], br, ar[mt][nt], 0, 0, 0);
        az[mt][nt] = __builtin_amdgcn_mfma_f32_16x16x32_bf16(a[mt], bz, az[mt][nt], 0, 0, 0);
      }
      if (kb < 4) {
        short8v bi = *(const short8v*)(wni + (size_t)c * 128 + koff);
#pragma unroll
        for (int mt = 0; mt < 4; ++mt)
          ain[mt][nt] = __builtin_amdgcn_mfma_f32_16x16x32_bf16(a[mt], bi, ain[mt][nt], 0, 0, 0);
      } else {
        short8v bh = *(const short8v*)(wnh + (size_t)c * 128 + (koff - 128));
#pragma unroll
        for (int mt = 0; mt < 4; ++mt)
          ahn[mt][nt] = __builtin_amdgcn_mfma_f32_16x16x32_bf16(a[mt], bh, ahn[mt][nt], 0, 0, 0);
      }
    }
  }

  __syncthreads();   // all MFMA reads of agg half done before transpose writes

#pragma unroll
  for (int nt = 0; nt < 2; ++nt) {
    const int c = cb + nt * 16 + rlo;
    const float brz_r = bih[c] + bhh[c];
    const float brz_z = bih[128 + c] + bhh[128 + c];
    const float b_in = bih[256 + c], b_hn = bhh[256 + c];
#pragma unroll
    for (int mt = 0; mt < 4; ++mt)
#pragma unroll
      for (int r = 0; r < 4; ++r) {
        const int nl = mt * 16 + kg * 4 + r;
        float hv = bf2f(xl[nl * 264 + 128 + c]);
        float rg = sigf(ar[mt][nt][r] + brz_r);
        float zz = sigf(az[mt][nt][r] + brz_z);
        float nn = tanhfast(ain[mt][nt][r] + b_in + rg * (ahn[mt][nt][r] + b_hn));
        xl[nl * 264 + c] = f2bf((1.0f - zz) * nn + zz * hv);
      }
  }
  __syncthreads();

  const int row = t >> 2, seg = t & 3;        // 32 channels (64B) per thread
  const unsigned short* src = xl + row * 264 + seg * 32;
  if (!last) {
    unsigned short* dst = houtb + (size_t)(n0 + row) * 128 + seg * 32;
    *(uint4*)(dst)      = *(const uint4*)(src);
    *(uint4*)(dst + 8)  = *(const uint4*)(src + 8);
    *(uint4*)(dst + 16) = *(const uint4*)(src + 16);
    *(uint4*)(dst + 24) = *(const uint4*)(src + 24);
  } else {
    float* dst = houtf + (size_t)(n0 + row) * 128 + seg * 32;
#pragma unroll
    for (int q = 0; q < 8; ++q) {
      float4 v;
      v.x = bf2f(src[q * 4 + 0]); v.y = bf2f(src[q * 4 + 1]);
      v.z = bf2f(src[q * 4 + 2]); v.w = bf2f(src[q * 4 + 3]);
      *(float4*)(dst + q * 4) = v;
    }
  }
}

// ---------------------------------------------------------------------------
// gated readout (fp32): one block per graph.
// ---------------------------------------------------------------------------
__global__ __launch_bounds__(256) void gated_kernel(
    const float* __restrict__ hn,
    const float* __restrict__ fmW,  const float* __restrict__ fmb,
    const float* __restrict__ gmW,  const float* __restrict__ gmb,
    const float* __restrict__ fmiW, const float* __restrict__ fmib,
    const float* __restrict__ gmiW, const float* __restrict__ gmib,
    float* __restrict__ hG, float* __restrict__ hGi)
{
  __shared__ float hn_t[32 * 132];
  __shared__ float g_lds[2][32];
  __shared__ float red[4][2][64];
  const int t = threadIdx.x;
  const int b = blockIdx.x;

#pragma unroll
  for (int i = 0; i < 4; ++i) {
    int e = t + 256 * i;
    int n = e >> 5, k4 = e & 31;
    ((float4*)(hn_t + n * 132))[k4] = ((const float4*)(hn + (size_t)b * 32 * 128))[e];
  }
  __syncthreads();

  if (t < 64) {
    const int head = t >> 5, i = t & 31;
    const float* gw = head ? gmiW : gmW;
    float s = 0.0f;
    for (int k = 0; k < 128; ++k) s = fmaf(hn_t[i * 132 + k], gw[k], s);
    s += head ? gmib[0] : gmb[0];
    g_lds[head][i] = sigf(s);
  }
  __syncthreads();

  const int s_ = t >> 2;
  const int q  = t & 3;
  float accf[8], accfi[8];
#pragma unroll
  for (int i = 0; i < 8; ++i) { accf[i] = 0.0f; accfi[i] = 0.0f; }

  const float4* w4  = (const float4*)(fmW  + (size_t)s_ * 128);
  const float4* wi4 = (const float4*)(fmiW + (size_t)s_ * 128);
  for (int k4 = 0; k4 < 32; ++k4) {
    float4 wf  = w4[k4];
    float4 wfi = wi4[k4];
#pragma unroll
    for (int i = 0; i < 8; ++i) {
      float4 h4 = *(const float4*)(hn_t + (q * 8 + i) * 132 + k4 * 4);
      accf[i]  = fmaf(h4.x, wf.x,  fmaf(h4.y, wf.y,  fmaf(h4.z, wf.z,  fmaf(h4.w, wf.w,  accf[i]))));
      accfi[i] = fmaf(h4.x, wfi.x, fmaf(h4.y, wfi.y, fmaf(h4.z, wfi.z, fmaf(h4.w, wfi.w, accfi[i]))));
    }
  }
  const float fb  = fmb[s_];
  const float fbi = fmib[s_];
  float pf = 0.0f, pfi = 0.0f;
#pragma unroll
  for (int i = 0; i < 8; ++i) {
    const int node = q * 8 + i;
    pf  += g_lds[0][node] * (accf[i]  + fb);
    pfi += g_lds[1][node] * (accfi[i] + fbi);
  }
  red[q][0][s_] = pf;
  red[q][1][s_] = pfi;
  __syncthreads();
  if (t < 64) {
    hG[(size_t)b * 64 + t] = red[0][0][t] + red[1][0][t] + red[2][0][t] + red[3][0][t];
  } else if (t < 128) {
    const int s2 = t - 64;
    hGi[(size_t)b * 64 + s2] = red[0][1][s2] + red[1][1][s2] + red[2][1][s2] + red[3][1][s2];
  }
}

// ---------------------------------------------------------------------------
extern "C" void kernel_launch(void* const* d_in, const int* in_sizes, int n_in,
                              void* d_out, int out_size, void* d_ws, size_t ws_size,
                              hipStream_t stream)
{
  (void)in_sizes; (void)n_in; (void)out_size; (void)ws_size;

  const float* h    = (const float*)d_in[0];
  const float* msgW = (const float*)d_in[1];
  const float* msgb = (const float*)d_in[2];
  const float* Wih  = (const float*)d_in[3];
  const float* Whh  = (const float*)d_in[4];
  const float* bih  = (const float*)d_in[5];
  const float* bhh  = (const float*)d_in[6];
  const float* fmW  = (const float*)d_in[7];
  const float* fmb  = (const float*)d_in[8];
  const float* gmW  = (const float*)d_in[9];
  const float* gmb  = (const float*)d_in[10];
  const float* fmiW = (const float*)d_in[11];
  const float* fmib = (const float*)d_in[12];
  const float* gmiW = (const float*)d_in[13];
  const float* gmib = (const float*)d_in[14];
  const int*   ei   = (const int*)d_in[15];
  const int* e0 = ei;
  const int* e1 = ei + EDGES;

  // ---- workspace carve ----
  char* w = (char*)d_ws;
  const size_t NF = (size_t)NNODE * NDIM_;
  unsigned short* P1b  = (unsigned short*)w;  w += NF * 2;
  unsigned short* P2b  = (unsigned short*)w;  w += NF * 2;
  unsigned short* aggb = (unsigned short*)w;  w += NF * 2;
  unsigned short* hb   = (unsigned short*)w;  w += NF * 2;
  unsigned short* hnb  = (unsigned short*)w;  w += NF * 2;
  int* cnt  = (int*)w;                        w += (size_t)NNODE * 4;
  int* offs = (int*)w;                        w += (size_t)(NNODE + 64) * 4;
  int* cur  = (int*)w;                        w += (size_t)NNODE * 4;
  int* adj  = (int*)w;                        w += (size_t)2 * EDGES * 4;
  int* bsum = (int*)w;                        w += 256 * 4;
  int* boff = (int*)w;                        w += 256 * 4;
  unsigned short* wm  = (unsigned short*)w;   w += (size_t)2 * 128 * 256 * 2;
  unsigned short* wrz = (unsigned short*)w;   w += (size_t)2 * 256 * 256 * 2;
  unsigned short* wni = (unsigned short*)w;   w += (size_t)2 * 128 * 128 * 2;
  unsigned short* wnh = (unsigned short*)w;   w += (size_t)2 * 128 * 128 * 2;

  float* out_hn  = (float*)d_out;
  float* out_hG  = out_hn + NF;
  float* out_hGi = out_hG + (size_t)B_ * SDIM_;

  // ---- one-time: conversions + CSR ----
  convert_w_kernel<<<512, 256, 0, stream>>>(msgW, Wih, Whh, wm, wrz, wni, wnh);
  convert_h_kernel<<<(int)(NF / 8 / 256), 256, 0, stream>>>(h, hb);
  hipMemsetAsync(cnt, 0, (size_t)NNODE * 4, stream);
  hist_kernel<<<EDGES / 256, 256, 0, stream>>>(e0, e1, cnt);
  scan1_kernel<<<NNODE / 256, 256, 0, stream>>>(cnt, offs, bsum);
  scan2_kernel<<<1, 256, 0, stream>>>(bsum, boff);
  scan3_kernel<<<NNODE / 256, 256, 0, stream>>>(cnt, offs, boff, cur);
  scatter_kernel<<<EDGES / 256, 256, 0, stream>>>(e0, e1, cur, adj);

  // ---- layers ----
  const unsigned short* hin = hb;
  for (int lyr = 0; lyr < 2; ++lyr) {
    proj_mfma_kernel<<<NNODE / 64, 256, 0, stream>>>(
        hin, wm + (size_t)lyr * 128 * 256, msgb + (size_t)lyr * 128, P1b, P2b);
    agg_kernel<<<NNODE / 4, 256, 0, stream>>>(P1b, P2b, offs, adj, aggb);
    gru_mfma_kernel<<<NNODE / 64, 256, 0, stream>>>(
        aggb, hin,
        wrz + (size_t)lyr * 256 * 256, wni + (size_t)lyr * 128 * 128,
        wnh + (size_t)lyr * 128 * 128,
        bih + (size_t)lyr * 384, bhh + (size_t)lyr * 384,
        hnb, out_hn, lyr);
    hin = hnb;
  }

  gated_kernel<<<B_, 256, 0, stream>>>(
      out_hn, fmW, fmb, gmW, gmb, fmiW, fmib, gmiW, gmib, out_hG, out_hGi);
}